// Round 1
// baseline (255.254 us; speedup 1.0000x reference)
//
#include <hip/hip_runtime.h>
#include <math.h>

// Problem constants
#define NIMG 8
#define HDIM 128
#define WDIM 128
#define MPIX (HDIM*WDIM)          // 16384
#define GNUM 64
#define DDIM 64
#define EDIM 32
#define UNK_CLASS 80
#define N_ERR4 8388608            // 8*256*128*128 / 4
#define NBLK 2048                 // total blocks: 512 density (b%4==0) + 1536 AE
#define AE_BLOCKS 1536
#define AE_STRIDE (AE_BLOCKS*256)

// Fused kernel: blocks with (b&3)==0 do density+matching (512 blocks = 8 imgs * 64),
// the rest grid-stride the 134MB err^2 reduction. Density blocks interleaved early
// so they are co-resident with AE blocks and their VALU work hides under HBM traffic.
__global__ __launch_bounds__(256) void fused_kernel(
    const float* __restrict__ err,        // [N,256,128,128]
    const float* __restrict__ err_map,    // [N,1,128,128]
    const float* __restrict__ gt_boxes,   // [N,64,4]
    const float* __restrict__ w1,         // [1,64]
    const float* __restrict__ b1,         // [64]
    const float* __restrict__ w2,         // [64,32]
    const float* __restrict__ b2,         // [32]
    const float* __restrict__ w3,         // [32,1]
    const float* __restrict__ b3,         // [1]
    const int*   __restrict__ gt_classes, // [N,64]
    float* __restrict__ ws)               // [NBLK] per-block partials
{
    const int t = threadIdx.x;
    const int b = blockIdx.x;
    float partial = 0.0f;

    __shared__ float4 sboxes[GNUM];
    __shared__ int    scls[GNUM];
    __shared__ float  sw1[DDIM], sb1[DDIM], sb2[EDIM], sw3[EDIM];
    __shared__ __align__(16) float sw2t[DDIM*EDIM];   // transposed: [e][d], d contiguous
    __shared__ float red[4];

    if ((b & 3) == 0) {
        // ---------------- density + anchor matching path ----------------
        const int db = b >> 2;           // 0..511
        const int n  = db >> 6;          // image
        const int m  = ((db & 63) << 8) | t;   // pixel in [0,16384)

        // stage per-image boxes/classes + weights into LDS
        if (t < GNUM)               sboxes[t]      = ((const float4*)gt_boxes)[n*GNUM + t];
        else if (t < 2*GNUM)        scls[t-GNUM]   = gt_classes[n*GNUM + (t-GNUM)];
        else if (t < 2*GNUM+DDIM) { sw1[t-128] = w1[t-128]; sb1[t-128] = b1[t-128]; }
        else if (t < 2*GNUM+DDIM+EDIM) { sb2[t-192] = b2[t-192]; sw3[t-192] = w3[t-192]; }
        for (int i = t; i < DDIM*EDIM; i += 256)
            sw2t[i] = w2[(i & 63)*EDIM + (i >> 6)];
        __syncthreads();

        // ---- anchors at this pixel (A=3 aspect ratios, detectron2 order) ----
        const float cx = (float)(m & (WDIM-1)) * 8.0f;
        const float cy = (float)(m >> 7) * 8.0f;
        const float s05 = sqrtf(0.5f), s2 = sqrtf(2.0f);
        const float hw0 = 0.5f*(32.0f/s05), hh0 = 0.5f*(32.0f*s05);
        const float hw1 = 16.0f,            hh1 = 16.0f;
        const float hw2 = 0.5f*(32.0f/s2),  hh2 = 0.5f*(32.0f*s2);

        const float ax1[3] = {cx-hw0, cx-hw1, cx-hw2};
        const float ay1[3] = {cy-hh0, cy-hh1, cy-hh2};
        const float ax2[3] = {cx+hw0, cx+hw1, cx+hw2};
        const float ay2[3] = {cy+hh0, cy+hh1, cy+hh2};
        float areaA[3];
        #pragma unroll
        for (int a = 0; a < 3; ++a) areaA[a] = (ax2[a]-ax1[a])*(ay2[a]-ay1[a]);

        // per-anchor best (division-free argmax: iou = inter/dn, dn >= 1e-9 > 0)
        float bi[3] = {-1.f,-1.f,-1.f}, bd[3] = {1.f,1.f,1.f};
        int   idx[3] = {0,0,0};

        for (int g = 0; g < GNUM; ++g) {
            const float4 bx = sboxes[g];                  // x1,y1,x2,y2 (LDS broadcast)
            const float areaB = (bx.z-bx.x)*(bx.w-bx.y);
            #pragma unroll
            for (int a = 0; a < 3; ++a) {
                float lx = fmaxf(bx.x, ax1[a]), ly = fmaxf(bx.y, ay1[a]);
                float rx = fminf(bx.z, ax2[a]), ry = fminf(bx.w, ay2[a]);
                float iw = fmaxf(rx-lx, 0.f),   ih = fmaxf(ry-ly, 0.f);
                float inter = iw*ih;
                float dn = fmaxf(areaB + areaA[a] - inter, 1e-9f);
                // strict > keeps FIRST max, matching jnp.argmax
                if (inter*bd[a] > bi[a]*dn) { bi[a]=inter; bd[a]=dn; idx[a]=g; }
            }
        }
        const bool unk = (scls[idx[0]] == UNK_CLASS) |
                         (scls[idx[1]] == UNK_CLASS) |
                         (scls[idx[2]] == UNK_CLASS);
        const float mask = unk ? 1.0f : 0.0f;

        // ---- density MLP: Linear(1,64)-ReLU-Linear(64,32)-ReLU-Linear(32,1) ----
        const float xv = err_map[(n << 14) + m];
        float h1[DDIM];
        #pragma unroll
        for (int d = 0; d < DDIM; ++d)
            h1[d] = fmaxf(fmaf(xv, sw1[d], sb1[d]), 0.0f);

        float p = b3[0];
        for (int e = 0; e < EDIM; ++e) {
            const float4* wr = (const float4*)&sw2t[e << 6];
            float a0=0.f, a1=0.f, a2=0.f, a3=0.f;
            #pragma unroll
            for (int q = 0; q < 16; ++q) {
                float4 wv = wr[q];                        // LDS broadcast read
                a0 = fmaf(h1[4*q+0], wv.x, a0);
                a1 = fmaf(h1[4*q+1], wv.y, a1);
                a2 = fmaf(h1[4*q+2], wv.z, a2);
                a3 = fmaf(h1[4*q+3], wv.w, a3);
            }
            float acc = sb2[e] + ((a0+a1)+(a2+a3));
            p = fmaf(fmaxf(acc, 0.0f), sw3[e], p);
        }

        // stable BCE-with-logits term: logaddexp(0,p) - p*mask
        partial = fmaxf(p, 0.0f) + log1pf(expf(-fabsf(p))) - p*mask;
    } else {
        // ---------------- AE sum-of-squares path (HBM streaming) ----------------
        const int ae = b - (b >> 2) - 1;                  // 0..1535
        const float4* e4 = (const float4*)err;
        float s0 = 0.f, s1 = 0.f;
        for (int i = ae*256 + t; i < N_ERR4; i += AE_STRIDE) {
            float4 v = e4[i];
            s0 = fmaf(v.x, v.x, s0);
            s1 = fmaf(v.y, v.y, s1);
            s0 = fmaf(v.z, v.z, s0);
            s1 = fmaf(v.w, v.w, s1);
        }
        partial = s0 + s1;
    }

    // ---- block reduction -> ws[blockIdx.x] ----
    float s = partial;
    #pragma unroll
    for (int off = 32; off > 0; off >>= 1) s += __shfl_xor(s, off, 64);
    if ((t & 63) == 0) red[t >> 6] = s;
    __syncthreads();
    if (t == 0) ws[b] = (red[0]+red[1]) + (red[2]+red[3]);
}

__global__ __launch_bounds__(256) void finalize_kernel(const float* __restrict__ ws,
                                                       float* __restrict__ out)
{
    const int t = threadIdx.x;
    float sd = 0.f, sa = 0.f;
    for (int i = t; i < NBLK; i += 256) {
        float v = ws[i];
        if ((i & 3) == 0) sd += v; else sa += v;
    }
    #pragma unroll
    for (int off = 32; off > 0; off >>= 1) {
        sd += __shfl_xor(sd, off, 64);
        sa += __shfl_xor(sa, off, 64);
    }
    __shared__ float rd[4], ra[4];
    if ((t & 63) == 0) { rd[t >> 6] = sd; ra[t >> 6] = sa; }
    __syncthreads();
    if (t == 0) {
        out[0] = ((ra[0]+ra[1])+(ra[2]+ra[3])) * (1.0f/33554432.0f); // loss_ae
        out[1] = ((rd[0]+rd[1])+(rd[2]+rd[3])) * (1.0f/131072.0f);   // loss_density
    }
}

extern "C" void kernel_launch(void* const* d_in, const int* in_sizes, int n_in,
                              void* d_out, int out_size, void* d_ws, size_t ws_size,
                              hipStream_t stream) {
    const float* err        = (const float*)d_in[0];
    const float* err_map    = (const float*)d_in[1];
    const float* gt_boxes   = (const float*)d_in[2];
    const float* w1         = (const float*)d_in[3];
    const float* b1         = (const float*)d_in[4];
    const float* w2         = (const float*)d_in[5];
    const float* b2         = (const float*)d_in[6];
    const float* w3         = (const float*)d_in[7];
    const float* b3         = (const float*)d_in[8];
    const int*   gt_classes = (const int*)d_in[9];
    float* out = (float*)d_out;
    float* ws  = (float*)d_ws;

    fused_kernel<<<NBLK, 256, 0, stream>>>(err, err_map, gt_boxes, w1, b1, w2, b2,
                                           w3, b3, gt_classes, ws);
    finalize_kernel<<<1, 256, 0, stream>>>(ws, out);
}

// Round 2
// 219.032 us; speedup vs baseline: 1.1654x; 1.1654x over previous
//
#include <hip/hip_runtime.h>
#include <math.h>

// Problem constants
#define NIMG 8
#define HDIM 128
#define WDIM 128
#define MPIX (HDIM*WDIM)          // 16384
#define GNUM 64
#define DDIM 64
#define EDIM 32
#define UNK_CLASS 80
#define N_ERR4 8388608            // 8*256*128*128 / 4 (float4 count)
#define NBLK 4096                 // AE blocks; first 512 also do density
#define DBLK 512
#define AE_THREADS (NBLK*256)     // 1048576; 8 float4 per thread exactly

// All 4096 blocks stream an exact 8-float4 share of err^2 with all 8 loads
// issued before consumption (8KB in flight per wave -> latency-tolerant).
// Blocks b<512 additionally do the density MLP + anchor matching afterwards;
// that VALU work overlaps the other blocks' HBM streaming.
__global__ __launch_bounds__(256) void fused_kernel(
    const float* __restrict__ err,        // [N,256,128,128]
    const float* __restrict__ err_map,    // [N,1,128,128]
    const float* __restrict__ gt_boxes,   // [N,64,4]
    const float* __restrict__ w1,         // [1,64]
    const float* __restrict__ b1,         // [64]
    const float* __restrict__ w2,         // [64,32]
    const float* __restrict__ b2,         // [32]
    const float* __restrict__ w3,         // [32,1]
    const float* __restrict__ b3,         // [1]
    const int*   __restrict__ gt_classes, // [N,64]
    float* __restrict__ ws)               // [NBLK] AE partials + [DBLK] density partials
{
    const int t = threadIdx.x;
    const int b = blockIdx.x;

    __shared__ float4 sboxes[GNUM];
    __shared__ int    scls[GNUM];
    __shared__ float  sw1[DDIM], sb1[DDIM], sb2[EDIM], sw3[EDIM];
    __shared__ __align__(16) float sw2t[DDIM*EDIM];   // transposed: [e][d], d contiguous
    __shared__ float redA[4], redD[4];

    // ---------------- AE sum-of-squares: 8 loads in flight ----------------
    const float4* __restrict__ e4 = (const float4*)err;
    const int gtid = (b << 8) | t;                    // [0, 1048576)
    float4 v0 = e4[gtid + 0*AE_THREADS];
    float4 v1 = e4[gtid + 1*AE_THREADS];
    float4 v2 = e4[gtid + 2*AE_THREADS];
    float4 v3 = e4[gtid + 3*AE_THREADS];
    float4 v4 = e4[gtid + 4*AE_THREADS];
    float4 v5 = e4[gtid + 5*AE_THREADS];
    float4 v6 = e4[gtid + 6*AE_THREADS];
    float4 v7 = e4[gtid + 7*AE_THREADS];
    float s0, s1, s2, s3;
    s0 = v0.x*v0.x; s1 = v0.y*v0.y; s2 = v0.z*v0.z; s3 = v0.w*v0.w;
    s0 = fmaf(v1.x,v1.x,s0); s1 = fmaf(v1.y,v1.y,s1); s2 = fmaf(v1.z,v1.z,s2); s3 = fmaf(v1.w,v1.w,s3);
    s0 = fmaf(v2.x,v2.x,s0); s1 = fmaf(v2.y,v2.y,s1); s2 = fmaf(v2.z,v2.z,s2); s3 = fmaf(v2.w,v2.w,s3);
    s0 = fmaf(v3.x,v3.x,s0); s1 = fmaf(v3.y,v3.y,s1); s2 = fmaf(v3.z,v3.z,s2); s3 = fmaf(v3.w,v3.w,s3);
    s0 = fmaf(v4.x,v4.x,s0); s1 = fmaf(v4.y,v4.y,s1); s2 = fmaf(v4.z,v4.z,s2); s3 = fmaf(v4.w,v4.w,s3);
    s0 = fmaf(v5.x,v5.x,s0); s1 = fmaf(v5.y,v5.y,s1); s2 = fmaf(v5.z,v5.z,s2); s3 = fmaf(v5.w,v5.w,s3);
    s0 = fmaf(v6.x,v6.x,s0); s1 = fmaf(v6.y,v6.y,s1); s2 = fmaf(v6.z,v6.z,s2); s3 = fmaf(v6.w,v6.w,s3);
    s0 = fmaf(v7.x,v7.x,s0); s1 = fmaf(v7.y,v7.y,s1); s2 = fmaf(v7.z,v7.z,s2); s3 = fmaf(v7.w,v7.w,s3);
    float aePart = (s0+s1) + (s2+s3);
    float dPart = 0.0f;

    if (b < DBLK) {
        // ---------------- density + anchor matching path ----------------
        const int n  = b >> 6;                 // image
        const int m  = ((b & 63) << 8) | t;    // pixel in [0,16384)

        if (t < GNUM)               sboxes[t]      = ((const float4*)gt_boxes)[n*GNUM + t];
        else if (t < 2*GNUM)        scls[t-GNUM]   = gt_classes[n*GNUM + (t-GNUM)];
        else if (t < 2*GNUM+DDIM) { sw1[t-128] = w1[t-128]; sb1[t-128] = b1[t-128]; }
        else if (t < 2*GNUM+DDIM+EDIM) { sb2[t-192] = b2[t-192]; sw3[t-192] = w3[t-192]; }
        for (int i = t; i < DDIM*EDIM; i += 256)
            sw2t[i] = w2[(i & 63)*EDIM + (i >> 6)];
        __syncthreads();

        // ---- anchors at this pixel (A=3 aspect ratios, detectron2 order) ----
        const float cx = (float)(m & (WDIM-1)) * 8.0f;
        const float cy = (float)(m >> 7) * 8.0f;
        const float s05 = sqrtf(0.5f), s2r = sqrtf(2.0f);
        const float hw0 = 0.5f*(32.0f/s05), hh0 = 0.5f*(32.0f*s05);
        const float hw1 = 16.0f,            hh1 = 16.0f;
        const float hw2 = 0.5f*(32.0f/s2r), hh2 = 0.5f*(32.0f*s2r);

        const float ax1[3] = {cx-hw0, cx-hw1, cx-hw2};
        const float ay1[3] = {cy-hh0, cy-hh1, cy-hh2};
        const float ax2[3] = {cx+hw0, cx+hw1, cx+hw2};
        const float ay2[3] = {cy+hh0, cy+hh1, cy+hh2};
        float areaA[3];
        #pragma unroll
        for (int a = 0; a < 3; ++a) areaA[a] = (ax2[a]-ax1[a])*(ay2[a]-ay1[a]);

        // per-anchor best GT (division-free argmax: iou = inter/dn, dn >= 1e-9 > 0)
        float bi[3] = {-1.f,-1.f,-1.f}, bd[3] = {1.f,1.f,1.f};
        int   idx[3] = {0,0,0};

        for (int g = 0; g < GNUM; ++g) {
            const float4 bx = sboxes[g];                  // LDS broadcast
            const float areaB = (bx.z-bx.x)*(bx.w-bx.y);
            #pragma unroll
            for (int a = 0; a < 3; ++a) {
                float lx = fmaxf(bx.x, ax1[a]), ly = fmaxf(bx.y, ay1[a]);
                float rx = fminf(bx.z, ax2[a]), ry = fminf(bx.w, ay2[a]);
                float iw = fmaxf(rx-lx, 0.f),   ih = fmaxf(ry-ly, 0.f);
                float inter = iw*ih;
                float dn = fmaxf(areaB + areaA[a] - inter, 1e-9f);
                // strict > keeps FIRST max, matching jnp.argmax
                if (inter*bd[a] > bi[a]*dn) { bi[a]=inter; bd[a]=dn; idx[a]=g; }
            }
        }
        const bool unk = (scls[idx[0]] == UNK_CLASS) |
                         (scls[idx[1]] == UNK_CLASS) |
                         (scls[idx[2]] == UNK_CLASS);
        const float mask = unk ? 1.0f : 0.0f;

        // ---- density MLP: Linear(1,64)-ReLU-Linear(64,32)-ReLU-Linear(32,1) ----
        const float xv = err_map[(n << 14) + m];
        float h1[DDIM];
        #pragma unroll
        for (int d = 0; d < DDIM; ++d)
            h1[d] = fmaxf(fmaf(xv, sw1[d], sb1[d]), 0.0f);

        float p = b3[0];
        for (int e = 0; e < EDIM; ++e) {
            const float4* wr = (const float4*)&sw2t[e << 6];
            float a0=0.f, a1=0.f, a2=0.f, a3=0.f;
            #pragma unroll
            for (int q = 0; q < 16; ++q) {
                float4 wv = wr[q];                        // LDS broadcast read
                a0 = fmaf(h1[4*q+0], wv.x, a0);
                a1 = fmaf(h1[4*q+1], wv.y, a1);
                a2 = fmaf(h1[4*q+2], wv.z, a2);
                a3 = fmaf(h1[4*q+3], wv.w, a3);
            }
            float acc = sb2[e] + ((a0+a1)+(a2+a3));
            p = fmaf(fmaxf(acc, 0.0f), sw3[e], p);
        }

        // stable BCE-with-logits term: logaddexp(0,p) - p*mask
        dPart = fmaxf(p, 0.0f) + log1pf(expf(-fabsf(p))) - p*mask;
    }

    // ---- block reduction (both sums in one butterfly) ----
    float x = aePart, y = dPart;
    #pragma unroll
    for (int off = 32; off > 0; off >>= 1) {
        x += __shfl_xor(x, off, 64);
        y += __shfl_xor(y, off, 64);
    }
    if ((t & 63) == 0) { redA[t >> 6] = x; redD[t >> 6] = y; }
    __syncthreads();
    if (t == 0) {
        ws[b] = (redA[0]+redA[1]) + (redA[2]+redA[3]);
        if (b < DBLK) ws[NBLK + b] = (redD[0]+redD[1]) + (redD[2]+redD[3]);
    }
}

__global__ __launch_bounds__(256) void finalize_kernel(const float* __restrict__ ws,
                                                       float* __restrict__ out)
{
    const int t = threadIdx.x;
    float sa = 0.f, sd = 0.f;
    for (int i = t; i < NBLK; i += 256) sa += ws[i];
    for (int i = t; i < DBLK; i += 256) sd += ws[NBLK + i];
    #pragma unroll
    for (int off = 32; off > 0; off >>= 1) {
        sa += __shfl_xor(sa, off, 64);
        sd += __shfl_xor(sd, off, 64);
    }
    __shared__ float ra[4], rd[4];
    if ((t & 63) == 0) { ra[t >> 6] = sa; rd[t >> 6] = sd; }
    __syncthreads();
    if (t == 0) {
        out[0] = ((ra[0]+ra[1])+(ra[2]+ra[3])) * (1.0f/33554432.0f); // loss_ae
        out[1] = ((rd[0]+rd[1])+(rd[2]+rd[3])) * (1.0f/131072.0f);   // loss_density
    }
}

extern "C" void kernel_launch(void* const* d_in, const int* in_sizes, int n_in,
                              void* d_out, int out_size, void* d_ws, size_t ws_size,
                              hipStream_t stream) {
    const float* err        = (const float*)d_in[0];
    const float* err_map    = (const float*)d_in[1];
    const float* gt_boxes   = (const float*)d_in[2];
    const float* w1         = (const float*)d_in[3];
    const float* b1         = (const float*)d_in[4];
    const float* w2         = (const float*)d_in[5];
    const float* b2         = (const float*)d_in[6];
    const float* w3         = (const float*)d_in[7];
    const float* b3         = (const float*)d_in[8];
    const int*   gt_classes = (const int*)d_in[9];
    float* out = (float*)d_out;
    float* ws  = (float*)d_ws;

    fused_kernel<<<NBLK, 256, 0, stream>>>(err, err_map, gt_boxes, w1, b1, w2, b2,
                                           w3, b3, gt_classes, ws);
    finalize_kernel<<<1, 256, 0, stream>>>(ws, out);
}

// Round 3
// 214.287 us; speedup vs baseline: 1.1912x; 1.0221x over previous
//
#include <hip/hip_runtime.h>
#include <math.h>

// Problem constants
#define NIMG 8
#define HDIM 128
#define WDIM 128
#define GNUM 64
#define DDIM 64
#define EDIM 32
#define UNK_CLASS 80
#define NBLK 4096                 // AE blocks; first 512 also do density
#define DBLK 512
#define AE_THREADS (NBLK*256)     // 1048576 threads; 8 float4 each, exact cover

// All 4096 blocks stream an exact 8-float4 share of err^2 (8KB in flight/wave).
// Blocks b<512 additionally run density MLP + anchor matching. The MLP is
// loop-swapped (acc[32] over layer-2 outputs, h1 recomputed per d) so peak
// VGPR stays < 64 -> 8 waves/SIMD (m69: occupancy halves at vgpr=64).
__global__ __launch_bounds__(256) void fused_kernel(
    const float* __restrict__ err,        // [N,256,128,128]
    const float* __restrict__ err_map,    // [N,1,128,128]
    const float* __restrict__ gt_boxes,   // [N,64,4]
    const float* __restrict__ w1,         // [1,64]
    const float* __restrict__ b1,         // [64]
    const float* __restrict__ w2,         // [64,32] row-major, row d contiguous
    const float* __restrict__ b2,         // [32]
    const float* __restrict__ w3,         // [32,1]
    const float* __restrict__ b3,         // [1]
    const int*   __restrict__ gt_classes, // [N,64]
    float* __restrict__ ws)               // [NBLK] AE partials + [DBLK] density partials
{
    const int t = threadIdx.x;
    const int b = blockIdx.x;

    __shared__ float4 sboxes[GNUM];
    __shared__ int    scls[GNUM];
    __shared__ float  sw1[DDIM], sb1[DDIM], sb2[EDIM], sw3[EDIM];
    __shared__ __align__(16) float sw2[DDIM*EDIM];    // raw copy of w2
    __shared__ float redA[4], redD[4];

    // ---------------- AE sum-of-squares: 8 loads in flight ----------------
    const float4* __restrict__ e4 = (const float4*)err;
    const int gtid = (b << 8) | t;                    // [0, 1048576)
    float4 v0 = e4[gtid + 0*AE_THREADS];
    float4 v1 = e4[gtid + 1*AE_THREADS];
    float4 v2 = e4[gtid + 2*AE_THREADS];
    float4 v3 = e4[gtid + 3*AE_THREADS];
    float4 v4 = e4[gtid + 4*AE_THREADS];
    float4 v5 = e4[gtid + 5*AE_THREADS];
    float4 v6 = e4[gtid + 6*AE_THREADS];
    float4 v7 = e4[gtid + 7*AE_THREADS];
    float s0, s1, s2, s3;
    s0 = v0.x*v0.x; s1 = v0.y*v0.y; s2 = v0.z*v0.z; s3 = v0.w*v0.w;
    s0 = fmaf(v1.x,v1.x,s0); s1 = fmaf(v1.y,v1.y,s1); s2 = fmaf(v1.z,v1.z,s2); s3 = fmaf(v1.w,v1.w,s3);
    s0 = fmaf(v2.x,v2.x,s0); s1 = fmaf(v2.y,v2.y,s1); s2 = fmaf(v2.z,v2.z,s2); s3 = fmaf(v2.w,v2.w,s3);
    s0 = fmaf(v3.x,v3.x,s0); s1 = fmaf(v3.y,v3.y,s1); s2 = fmaf(v3.z,v3.z,s2); s3 = fmaf(v3.w,v3.w,s3);
    s0 = fmaf(v4.x,v4.x,s0); s1 = fmaf(v4.y,v4.y,s1); s2 = fmaf(v4.z,v4.z,s2); s3 = fmaf(v4.w,v4.w,s3);
    s0 = fmaf(v5.x,v5.x,s0); s1 = fmaf(v5.y,v5.y,s1); s2 = fmaf(v5.z,v5.z,s2); s3 = fmaf(v5.w,v5.w,s3);
    s0 = fmaf(v6.x,v6.x,s0); s1 = fmaf(v6.y,v6.y,s1); s2 = fmaf(v6.z,v6.z,s2); s3 = fmaf(v6.w,v6.w,s3);
    s0 = fmaf(v7.x,v7.x,s0); s1 = fmaf(v7.y,v7.y,s1); s2 = fmaf(v7.z,v7.z,s2); s3 = fmaf(v7.w,v7.w,s3);
    float aePart = (s0+s1) + (s2+s3);
    float dPart = 0.0f;

    if (b < DBLK) {
        // ---------------- density + anchor matching path ----------------
        const int n  = b >> 6;                 // image
        const int m  = ((b & 63) << 8) | t;    // pixel in [0,16384)

        if (t < GNUM)               sboxes[t]      = ((const float4*)gt_boxes)[n*GNUM + t];
        else if (t < 2*GNUM)        scls[t-GNUM]   = gt_classes[n*GNUM + (t-GNUM)];
        else if (t < 2*GNUM+DDIM) { sw1[t-128] = w1[t-128]; sb1[t-128] = b1[t-128]; }
        else if (t < 2*GNUM+DDIM+EDIM) { sb2[t-192] = b2[t-192]; sw3[t-192] = w3[t-192]; }
        for (int i = t; i < DDIM*EDIM; i += 256)
            sw2[i] = w2[i];                               // no transpose needed
        __syncthreads();

        // ---- anchors at this pixel (A=3 aspect ratios, detectron2 order) ----
        const float cx = (float)(m & (WDIM-1)) * 8.0f;
        const float cy = (float)(m >> 7) * 8.0f;
        const float s05 = sqrtf(0.5f), s2r = sqrtf(2.0f);
        const float hw0 = 0.5f*(32.0f/s05), hh0 = 0.5f*(32.0f*s05);
        const float hw1 = 16.0f,            hh1 = 16.0f;
        const float hw2 = 0.5f*(32.0f/s2r), hh2 = 0.5f*(32.0f*s2r);

        const float ax1[3] = {cx-hw0, cx-hw1, cx-hw2};
        const float ay1[3] = {cy-hh0, cy-hh1, cy-hh2};
        const float ax2[3] = {cx+hw0, cx+hw1, cx+hw2};
        const float ay2[3] = {cy+hh0, cy+hh1, cy+hh2};
        float areaA[3];
        #pragma unroll
        for (int a = 0; a < 3; ++a) areaA[a] = (ax2[a]-ax1[a])*(ay2[a]-ay1[a]);

        // per-anchor best GT (division-free argmax: iou = inter/dn, dn > 0)
        float bi[3] = {-1.f,-1.f,-1.f}, bd[3] = {1.f,1.f,1.f};
        int   idx[3] = {0,0,0};

        for (int g = 0; g < GNUM; ++g) {
            const float4 bx = sboxes[g];                  // LDS broadcast
            const float areaB = (bx.z-bx.x)*(bx.w-bx.y);
            #pragma unroll
            for (int a = 0; a < 3; ++a) {
                float lx = fmaxf(bx.x, ax1[a]), ly = fmaxf(bx.y, ay1[a]);
                float rx = fminf(bx.z, ax2[a]), ry = fminf(bx.w, ay2[a]);
                float iw = fmaxf(rx-lx, 0.f),   ih = fmaxf(ry-ly, 0.f);
                float inter = iw*ih;
                float dn = fmaxf(areaB + areaA[a] - inter, 1e-9f);
                // strict > keeps FIRST max, matching jnp.argmax
                if (inter*bd[a] > bi[a]*dn) { bi[a]=inter; bd[a]=dn; idx[a]=g; }
            }
        }
        const bool unk = (scls[idx[0]] == UNK_CLASS) |
                         (scls[idx[1]] == UNK_CLASS) |
                         (scls[idx[2]] == UNK_CLASS);
        const float mask = unk ? 1.0f : 0.0f;

        // ---- density MLP, loop-swapped: acc[32] over layer-2 outputs ----
        // h1[d] = relu(xv*w1[d]+b1[d]) recomputed per d (2 ops) -> no h1[64] array
        const float xv = err_map[(n << 14) + m];
        float acc[EDIM];
        #pragma unroll
        for (int e = 0; e < EDIM; ++e) acc[e] = sb2[e];

        const float4* __restrict__ sw2v = (const float4*)sw2;
        for (int d = 0; d < DDIM; ++d) {
            const float h = fmaxf(fmaf(xv, sw1[d], sb1[d]), 0.0f);
            #pragma unroll
            for (int j = 0; j < 8; ++j) {
                float4 wv = sw2v[(d << 3) + j];           // LDS broadcast (row d of w2)
                acc[4*j+0] = fmaf(h, wv.x, acc[4*j+0]);
                acc[4*j+1] = fmaf(h, wv.y, acc[4*j+1]);
                acc[4*j+2] = fmaf(h, wv.z, acc[4*j+2]);
                acc[4*j+3] = fmaf(h, wv.w, acc[4*j+3]);
            }
        }
        float p = b3[0];
        #pragma unroll
        for (int e = 0; e < EDIM; ++e)
            p = fmaf(fmaxf(acc[e], 0.0f), sw3[e], p);

        // stable BCE-with-logits term: logaddexp(0,p) - p*mask
        dPart = fmaxf(p, 0.0f) + log1pf(expf(-fabsf(p))) - p*mask;
    }

    // ---- block reduction (both sums in one butterfly) ----
    float x = aePart, y = dPart;
    #pragma unroll
    for (int off = 32; off > 0; off >>= 1) {
        x += __shfl_xor(x, off, 64);
        y += __shfl_xor(y, off, 64);
    }
    if ((t & 63) == 0) { redA[t >> 6] = x; redD[t >> 6] = y; }
    __syncthreads();
    if (t == 0) {
        ws[b] = (redA[0]+redA[1]) + (redA[2]+redA[3]);
        if (b < DBLK) ws[NBLK + b] = (redD[0]+redD[1]) + (redD[2]+redD[3]);
    }
}

__global__ __launch_bounds__(256) void finalize_kernel(const float* __restrict__ ws,
                                                       float* __restrict__ out)
{
    const int t = threadIdx.x;
    float sa = 0.f, sd = 0.f;
    for (int i = t; i < NBLK; i += 256) sa += ws[i];
    for (int i = t; i < DBLK; i += 256) sd += ws[NBLK + i];
    #pragma unroll
    for (int off = 32; off > 0; off >>= 1) {
        sa += __shfl_xor(sa, off, 64);
        sd += __shfl_xor(sd, off, 64);
    }
    __shared__ float ra[4], rd[4];
    if ((t & 63) == 0) { ra[t >> 6] = sa; rd[t >> 6] = sd; }
    __syncthreads();
    if (t == 0) {
        out[0] = ((ra[0]+ra[1])+(ra[2]+ra[3])) * (1.0f/33554432.0f); // loss_ae
        out[1] = ((rd[0]+rd[1])+(rd[2]+rd[3])) * (1.0f/131072.0f);   // loss_density
    }
}

extern "C" void kernel_launch(void* const* d_in, const int* in_sizes, int n_in,
                              void* d_out, int out_size, void* d_ws, size_t ws_size,
                              hipStream_t stream) {
    const float* err        = (const float*)d_in[0];
    const float* err_map    = (const float*)d_in[1];
    const float* gt_boxes   = (const float*)d_in[2];
    const float* w1         = (const float*)d_in[3];
    const float* b1         = (const float*)d_in[4];
    const float* w2         = (const float*)d_in[5];
    const float* b2         = (const float*)d_in[6];
    const float* w3         = (const float*)d_in[7];
    const float* b3         = (const float*)d_in[8];
    const int*   gt_classes = (const int*)d_in[9];
    float* out = (float*)d_out;
    float* ws  = (float*)d_ws;

    fused_kernel<<<NBLK, 256, 0, stream>>>(err, err_map, gt_boxes, w1, b1, w2, b2,
                                           w3, b3, gt_classes, ws);
    finalize_kernel<<<1, 256, 0, stream>>>(ws, out);
}